// Round 13
// baseline (192.753 us; speedup 1.0000x reference)
//
#include <hip/hip_runtime.h>

#define TOPK 32

// ---------------------------------------------------------------------------
// K0: per-batch histogram of pos -> counts. B blocks, LDS atomics. ~4us.
// ---------------------------------------------------------------------------
__global__ void hist_kernel(const int* __restrict__ pos,
                            int* __restrict__ counts,
                            int S) {
    extern __shared__ int cnt[];          // S ints
    int b = blockIdx.x;
    int t = threadIdx.x;
    for (int i = t; i < S; i += 256) cnt[i] = 0;
    __syncthreads();
    for (int i = t; i < S; i += 256)
        atomicAdd(&cnt[pos[(size_t)b * S + i]], 1);
    __syncthreads();
    for (int i = t; i < S; i += 256)
        counts[(size_t)b * S + i] = cnt[i];
}

// ---------------------------------------------------------------------------
// K1: one wave per row; dot ONLY for referenced rows (count>0, ~63%).
//   d2[row] = dot(base[row,:], W[b,:])
// ---------------------------------------------------------------------------
__global__ void dot_kernel(const float* __restrict__ base,
                           const float* __restrict__ bw,
                           const int* __restrict__ counts,
                           float* __restrict__ d2,
                           int S, int H) {
    int wid  = (blockIdx.x * blockDim.x + threadIdx.x) >> 6;  // row = b*S + p
    int lane = threadIdx.x & 63;
    if (counts[wid] == 0) return;
    int b = wid / S;

    const float4* row = (const float4*)(base + (size_t)wid * H);
    const float4* w4  = (const float4*)(bw + (size_t)b * H);
    int n4 = H >> 2;                      // 512

    float acc = 0.f;
    #pragma unroll 8
    for (int i = lane; i < n4; i += 64) {
        float4 v = row[i];
        float4 w = w4[i];
        acc += v.x * w.x + v.y * w.y + v.z * w.z + v.w * w.w;
    }
    #pragma unroll
    for (int off = 32; off > 0; off >>= 1)
        acc += __shfl_down(acc, off, 64);

    if (lane == 0) d2[wid] = acc;
}

// ---------------------------------------------------------------------------
// K2: blocks 0..B-1: per-batch gather d2 -> detect, exact top-32 by a single
//     wave (ties -> lower index = lax.top_k), nontopk, mean.
//     blocks B.. : stream-copy mixed=base for count==0 rows (~37%) --
//     hides the serial top-k. PLAIN loads/stores (NT removed: A/B test).
// ---------------------------------------------------------------------------
__global__ void topk_copy_kernel(const float* __restrict__ d2,
                                 const int* __restrict__ pos,
                                 const int* __restrict__ counts,
                                 const float* __restrict__ base,
                                 float* __restrict__ mixed,
                                 float* __restrict__ detect,
                                 float* __restrict__ nontopk,
                                 float* __restrict__ meanv,
                                 int B, int S, int H, int nblocks) {
    __shared__ float smem[8192];          // dvals[S] + vals[S], S==4096
    int t = threadIdx.x;

    if (blockIdx.x < B) {
        float* dvals = smem;
        float* vals  = smem + S;
        int b = blockIdx.x;

        for (int i = t; i < S; i += 256)
            dvals[i] = d2[(size_t)b * S + i];
        __syncthreads();
        for (int i = t; i < S; i += 256) {
            float v = fmaxf(dvals[pos[(size_t)b * S + i]], 0.f);
            vals[i] = v;
            detect[(size_t)b * S + i] = v;
        }
        __syncthreads();

        if (t < 64) {                     // single wave: barrier-free top-k
            int lane = t;
            float sum = 0.f;
            for (int it = 0; it < TOPK; ++it) {
                float lv = -INFINITY;
                int   li = 0x7fffffff;
                for (int c = lane * 4; c < S; c += 256) {
                    float4 v = *(const float4*)&vals[c];
                    if (v.x > lv) { lv = v.x; li = c; }
                    if (v.y > lv) { lv = v.y; li = c + 1; }
                    if (v.z > lv) { lv = v.z; li = c + 2; }
                    if (v.w > lv) { lv = v.w; li = c + 3; }
                }
                #pragma unroll
                for (int off = 32; off > 0; off >>= 1) {
                    float ov = __shfl_down(lv, off, 64);
                    int   oi = __shfl_down(li, off, 64);
                    if (ov > lv || (ov == lv && oi < li)) { lv = ov; li = oi; }
                }
                lv = __shfl(lv, 0, 64);
                li = __shfl(li, 0, 64);
                sum += lv;
                if (lane == 0) vals[li] = -INFINITY;  // wave-synchronous
            }
            if (lane == 0) meanv[b] = sum / (float)TOPK;
        }
        __syncthreads();
        for (int i = t; i < S; i += 256) {
            float v = vals[i];
            nontopk[(size_t)b * S + i] = (v == -INFINITY) ? 0.f : v;
        }
    } else {
        int nrows = B * S;
        int ncopy = nblocks - B;
        int n4 = H >> 2;                  // 512
        for (int row = blockIdx.x - B; row < nrows; row += ncopy) {
            if (counts[row] != 0) continue;
            const float4* bp = (const float4*)(base + (size_t)row * H);
            float4*       op = (float4*)(mixed + (size_t)row * H);
            #pragma unroll 2
            for (int i = t; i < n4; i += 256)
                op[i] = bp[i];
        }
    }
}

// ---------------------------------------------------------------------------
// K3: 4 consecutive rows per block; ONLY count>0 rows (~63%):
//   mixed[b,p,:] = base[b,p,:] + counts[b,p]*mean[b]*W[b,:]
// PLAIN stores (NT removed: A/B test).
// ---------------------------------------------------------------------------
__global__ void mix_kernel(const float* __restrict__ base,
                           const float* __restrict__ bw,
                           const int* __restrict__ counts,
                           const float* __restrict__ meanv,
                           float* __restrict__ mixed,
                           int S, int H) {
    int r0 = blockIdx.x << 2;
    int b  = r0 / S;
    const float4* w4 = (const float4*)(bw + (size_t)b * H);
    float mb = meanv[b];
    int n4 = H >> 2;                      // 512

    for (int r = r0; r < r0 + 4; ++r) {
        int c = counts[r];
        if (c == 0) continue;             // copied by K2
        float scale = (float)c * mb;
        const float4* b4 = (const float4*)(base + (size_t)r * H);
        float4*       o4 = (float4*)(mixed + (size_t)r * H);
        #pragma unroll 2
        for (int i = threadIdx.x; i < n4; i += blockDim.x) {
            float4 v = b4[i];
            float4 w = w4[i];
            float4 o;
            o.x = v.x + scale * w.x;
            o.y = v.y + scale * w.y;
            o.z = v.z + scale * w.z;
            o.w = v.w + scale * w.w;
            o4[i] = o;
        }
    }
}

// ---------------------------------------------------------------------------
extern "C" void kernel_launch(void* const* d_in, const int* in_sizes, int n_in,
                              void* d_out, int out_size, void* d_ws, size_t ws_size,
                              hipStream_t stream) {
    const float* base = (const float*)d_in[0];
    const int*   pos  = (const int*)d_in[1];
    const float* bw   = (const float*)d_in[2];

    long n0 = in_sizes[0];               // B*S*H
    long n1 = in_sizes[1];               // B*S
    long n2 = in_sizes[2];               // B*H
    int H = (int)(n0 / n1);
    int B = (int)(n2 / H);
    int S = (int)(n1 / B);

    float* out_mixed   = (float*)d_out;
    float* out_detect  = out_mixed + (size_t)B * S * H;
    float* out_nontopk = out_detect + (size_t)B * S;

    int*   counts = (int*)d_ws;
    float* d2     = (float*)((char*)d_ws + (size_t)B * S * sizeof(int));
    float* meanv  = (float*)((char*)d_ws + 2 * (size_t)B * S * sizeof(int));

    int nrows = B * S;
    int nk2   = B + 1024;                // 8 topk blocks + 1024 copy blocks

    hist_kernel<<<B, 256, (size_t)S * sizeof(int), stream>>>(pos, counts, S);
    dot_kernel<<<nrows / 4, 256, 0, stream>>>(base, bw, counts, d2, S, H);
    topk_copy_kernel<<<nk2, 256, 0, stream>>>(
        d2, pos, counts, base, out_mixed, out_detect, out_nontopk, meanv,
        B, S, H, nk2);
    mix_kernel<<<nrows / 4, 256, 0, stream>>>(base, bw, counts, meanv, out_mixed, S, H);
}

// Round 14
// 178.609 us; speedup vs baseline: 1.0792x; 1.0792x over previous
//
#include <hip/hip_runtime.h>

#define TOPK 32

typedef float vfloat4 __attribute__((ext_vector_type(4)));

// ---------------------------------------------------------------------------
// K0: per-batch histogram of pos -> counts. B blocks, LDS atomics. ~4us.
// ---------------------------------------------------------------------------
__global__ void hist_kernel(const int* __restrict__ pos,
                            int* __restrict__ counts,
                            int S) {
    extern __shared__ int cnt[];          // S ints
    int b = blockIdx.x;
    int t = threadIdx.x;
    for (int i = t; i < S; i += 256) cnt[i] = 0;
    __syncthreads();
    for (int i = t; i < S; i += 256)
        atomicAdd(&cnt[pos[(size_t)b * S + i]], 1);
    __syncthreads();
    for (int i = t; i < S; i += 256)
        counts[(size_t)b * S + i] = cnt[i];
}

// ---------------------------------------------------------------------------
// K1: one wave per row; dot ONLY for referenced rows (count>0, ~63%).
//   d2[row] = dot(base[row,:], W[b,:])
// Cached loads: primes L3 with the rows mix re-reads (R10: ~130MB survives).
// ---------------------------------------------------------------------------
__global__ void dot_kernel(const float* __restrict__ base,
                           const float* __restrict__ bw,
                           const int* __restrict__ counts,
                           float* __restrict__ d2,
                           int S, int H) {
    int wid  = (blockIdx.x * blockDim.x + threadIdx.x) >> 6;  // row = b*S + p
    int lane = threadIdx.x & 63;
    if (counts[wid] == 0) return;
    int b = wid / S;

    const float4* row = (const float4*)(base + (size_t)wid * H);
    const float4* w4  = (const float4*)(bw + (size_t)b * H);
    int n4 = H >> 2;                      // 512

    float acc = 0.f;
    #pragma unroll 8
    for (int i = lane; i < n4; i += 64) {
        float4 v = row[i];
        float4 w = w4[i];
        acc += v.x * w.x + v.y * w.y + v.z * w.z + v.w * w.w;
    }
    #pragma unroll
    for (int off = 32; off > 0; off >>= 1)
        acc += __shfl_down(acc, off, 64);

    if (lane == 0) d2[wid] = acc;
}

// ---------------------------------------------------------------------------
// K2: blocks 0..B-1: per-batch gather d2 -> detect, exact top-32 by a single
//     wave (ties -> lower index = lax.top_k), nontopk, mean.
//     blocks B.. : copy mixed=base for count==0 rows in CONTIGUOUS 32-row
//     chunks -- counts fetched in one coalesced burst to LDS (no serial
//     pointer-chase), rows dense. NT both ways. Hides the serial top-k.
// ---------------------------------------------------------------------------
__global__ void topk_copy_kernel(const float* __restrict__ d2,
                                 const int* __restrict__ pos,
                                 const int* __restrict__ counts,
                                 const float* __restrict__ base,
                                 float* __restrict__ mixed,
                                 float* __restrict__ detect,
                                 float* __restrict__ nontopk,
                                 float* __restrict__ meanv,
                                 int B, int S, int H) {
    __shared__ float smem[8192];          // dvals[S] + vals[S], S==4096
    __shared__ int ccnt[32];
    int t = threadIdx.x;

    if (blockIdx.x < B) {
        float* dvals = smem;
        float* vals  = smem + S;
        int b = blockIdx.x;

        for (int i = t; i < S; i += 256)
            dvals[i] = d2[(size_t)b * S + i];
        __syncthreads();
        for (int i = t; i < S; i += 256) {
            float v = fmaxf(dvals[pos[(size_t)b * S + i]], 0.f);
            vals[i] = v;
            detect[(size_t)b * S + i] = v;
        }
        __syncthreads();

        if (t < 64) {                     // single wave: barrier-free top-k
            int lane = t;
            float sum = 0.f;
            for (int it = 0; it < TOPK; ++it) {
                float lv = -INFINITY;
                int   li = 0x7fffffff;
                for (int c = lane * 4; c < S; c += 256) {
                    float4 v = *(const float4*)&vals[c];
                    if (v.x > lv) { lv = v.x; li = c; }
                    if (v.y > lv) { lv = v.y; li = c + 1; }
                    if (v.z > lv) { lv = v.z; li = c + 2; }
                    if (v.w > lv) { lv = v.w; li = c + 3; }
                }
                #pragma unroll
                for (int off = 32; off > 0; off >>= 1) {
                    float ov = __shfl_down(lv, off, 64);
                    int   oi = __shfl_down(li, off, 64);
                    if (ov > lv || (ov == lv && oi < li)) { lv = ov; li = oi; }
                }
                lv = __shfl(lv, 0, 64);
                li = __shfl(li, 0, 64);
                sum += lv;
                if (lane == 0) vals[li] = -INFINITY;  // wave-synchronous
            }
            if (lane == 0) meanv[b] = sum / (float)TOPK;
        }
        __syncthreads();
        for (int i = t; i < S; i += 256) {
            float v = vals[i];
            nontopk[(size_t)b * S + i] = (v == -INFINITY) ? 0.f : v;
        }
    } else {
        int r0 = (blockIdx.x - B) << 5;   // 32 consecutive rows per block
        int n4 = H >> 2;                  // 512
        if (t < 32) ccnt[t] = counts[r0 + t];   // one coalesced burst
        __syncthreads();
        for (int k = 0; k < 32; ++k) {
            if (ccnt[k] != 0) continue;
            const vfloat4* bp = (const vfloat4*)(base + (size_t)(r0 + k) * H);
            vfloat4*       op = (vfloat4*)(mixed + (size_t)(r0 + k) * H);
            #pragma unroll 2
            for (int i = t; i < n4; i += 256) {
                vfloat4 v = __builtin_nontemporal_load(&bp[i]);
                __builtin_nontemporal_store(v, &op[i]);
            }
        }
    }
}

// ---------------------------------------------------------------------------
// K3: mix over CONTIGUOUS 32-row chunks; ONLY count>0 rows (~63%):
//   mixed[b,p,:] = base[b,p,:] + counts[b,p]*mean[b]*W[b,:]
// counts burst to LDS; plain loads (L3 hits from dot), NT stores.
// ---------------------------------------------------------------------------
__global__ void mix_kernel(const float* __restrict__ base,
                           const float* __restrict__ bw,
                           const int* __restrict__ counts,
                           const float* __restrict__ meanv,
                           float* __restrict__ mixed,
                           int S, int H) {
    __shared__ int ccnt[32];
    int t = threadIdx.x;
    int r0 = blockIdx.x << 5;             // 32 consecutive rows per block
    int b  = r0 / S;                      // 32 | S -> no batch straddle
    const float4* w4 = (const float4*)(bw + (size_t)b * H);
    float mb = meanv[b];
    int n4 = H >> 2;                      // 512

    if (t < 32) ccnt[t] = counts[r0 + t]; // one coalesced burst
    __syncthreads();

    for (int k = 0; k < 32; ++k) {
        int c = ccnt[k];
        if (c == 0) continue;             // copied by K2
        float scale = (float)c * mb;
        const float4* b4 = (const float4*)(base + (size_t)(r0 + k) * H);
        vfloat4*      o4 = (vfloat4*)(mixed + (size_t)(r0 + k) * H);
        #pragma unroll 2
        for (int i = t; i < n4; i += 256) {
            float4 v = b4[i];
            float4 w = w4[i];
            vfloat4 o;
            o.x = v.x + scale * w.x;
            o.y = v.y + scale * w.y;
            o.z = v.z + scale * w.z;
            o.w = v.w + scale * w.w;
            __builtin_nontemporal_store(o, &o4[i]);
        }
    }
}

// ---------------------------------------------------------------------------
extern "C" void kernel_launch(void* const* d_in, const int* in_sizes, int n_in,
                              void* d_out, int out_size, void* d_ws, size_t ws_size,
                              hipStream_t stream) {
    const float* base = (const float*)d_in[0];
    const int*   pos  = (const int*)d_in[1];
    const float* bw   = (const float*)d_in[2];

    long n0 = in_sizes[0];               // B*S*H
    long n1 = in_sizes[1];               // B*S
    long n2 = in_sizes[2];               // B*H
    int H = (int)(n0 / n1);
    int B = (int)(n2 / H);
    int S = (int)(n1 / B);

    float* out_mixed   = (float*)d_out;
    float* out_detect  = out_mixed + (size_t)B * S * H;
    float* out_nontopk = out_detect + (size_t)B * S;

    int*   counts = (int*)d_ws;
    float* d2     = (float*)((char*)d_ws + (size_t)B * S * sizeof(int));
    float* meanv  = (float*)((char*)d_ws + 2 * (size_t)B * S * sizeof(int));

    int nrows   = B * S;
    int nchunks = nrows / 32;            // 1024 contiguous 32-row chunks

    hist_kernel<<<B, 256, (size_t)S * sizeof(int), stream>>>(pos, counts, S);
    dot_kernel<<<nrows / 4, 256, 0, stream>>>(base, bw, counts, d2, S, H);
    topk_copy_kernel<<<B + nchunks, 256, 0, stream>>>(
        d2, pos, counts, base, out_mixed, out_detect, out_nontopk, meanv,
        B, S, H);
    mix_kernel<<<nchunks, 256, 0, stream>>>(base, bw, counts, meanv, out_mixed, S, H);
}

// Round 15
// 169.702 us; speedup vs baseline: 1.1358x; 1.0525x over previous
//
#include <hip/hip_runtime.h>

// Problem shapes are fixed by the reference: B=8, S=4096, H=2048.
#define BB 8
#define SS 4096
#define HH 2048
#define N4 (HH / 4)      // 512 float4 per row
#define TOPK 32

typedef float vfloat4 __attribute__((ext_vector_type(4)));

// ---------------------------------------------------------------------------
// K0: per-batch histogram of pos -> counts. B blocks, LDS atomics. ~4us.
// ---------------------------------------------------------------------------
__global__ void hist_kernel(const int* __restrict__ pos,
                            int* __restrict__ counts) {
    __shared__ int cnt[SS];
    int b = blockIdx.x;
    int t = threadIdx.x;
    #pragma unroll
    for (int i = t; i < SS; i += 256) cnt[i] = 0;
    __syncthreads();
    #pragma unroll
    for (int i = t; i < SS; i += 256)
        atomicAdd(&cnt[pos[(size_t)b * SS + i]], 1);
    __syncthreads();
    #pragma unroll
    for (int i = t; i < SS; i += 256)
        counts[(size_t)b * SS + i] = cnt[i];
}

// ---------------------------------------------------------------------------
// K1: one wave per row; dot ONLY for referenced rows (count>0, ~63%).
//   d2[row] = dot(base[row,:], W[b,:])
// ALL 16 loads issued up-front with compile-time offsets (no runtime-bound
// loop -> no guarded clusters -> full memory-level parallelism), then an
// FMA tree and a wave shuffle-reduce.
// ---------------------------------------------------------------------------
__global__ __launch_bounds__(256)
void dot_kernel(const float* __restrict__ base,
                const float* __restrict__ bw,
                const int* __restrict__ counts,
                float* __restrict__ d2) {
    int wid  = (blockIdx.x * 256 + threadIdx.x) >> 6;   // row = b*S + p
    int lane = threadIdx.x & 63;
    if (counts[wid] == 0) return;
    int b = wid >> 12;                                  // / SS

    const float4* rp = (const float4*)(base + (size_t)wid * HH) + lane;
    const float4* wp = (const float4*)(bw + (size_t)b * HH) + lane;

    float4 r0 = rp[0],   r1 = rp[64],  r2 = rp[128], r3 = rp[192];
    float4 r4 = rp[256], r5 = rp[320], r6 = rp[384], r7 = rp[448];
    float4 w0 = wp[0],   w1 = wp[64],  w2 = wp[128], w3 = wp[192];
    float4 w4 = wp[256], w5 = wp[320], w6 = wp[384], w7 = wp[448];

    float s0 = r0.x*w0.x + r0.y*w0.y + r0.z*w0.z + r0.w*w0.w;
    float s1 = r1.x*w1.x + r1.y*w1.y + r1.z*w1.z + r1.w*w1.w;
    float s2 = r2.x*w2.x + r2.y*w2.y + r2.z*w2.z + r2.w*w2.w;
    float s3 = r3.x*w3.x + r3.y*w3.y + r3.z*w3.z + r3.w*w3.w;
    float s4 = r4.x*w4.x + r4.y*w4.y + r4.z*w4.z + r4.w*w4.w;
    float s5 = r5.x*w5.x + r5.y*w5.y + r5.z*w5.z + r5.w*w5.w;
    float s6 = r6.x*w6.x + r6.y*w6.y + r6.z*w6.z + r6.w*w6.w;
    float s7 = r7.x*w7.x + r7.y*w7.y + r7.z*w7.z + r7.w*w7.w;
    float acc = ((s0 + s1) + (s2 + s3)) + ((s4 + s5) + (s6 + s7));

    #pragma unroll
    for (int off = 32; off > 0; off >>= 1)
        acc += __shfl_down(acc, off, 64);

    if (lane == 0) d2[wid] = acc;
}

// ---------------------------------------------------------------------------
// K2: blocks 0..B-1: per-batch gather d2 -> detect, exact top-32 by a single
//     wave (ties -> lower index = lax.top_k), nontopk, mean.
//     blocks B.. : stream-copy mixed=base for count==0 rows (~37%), NT both
//     ways -- hides the serial top-k. (R9 structure: best measured.)
// ---------------------------------------------------------------------------
__global__ void topk_copy_kernel(const float* __restrict__ d2,
                                 const int* __restrict__ pos,
                                 const int* __restrict__ counts,
                                 const float* __restrict__ base,
                                 float* __restrict__ mixed,
                                 float* __restrict__ detect,
                                 float* __restrict__ nontopk,
                                 float* __restrict__ meanv,
                                 int nblocks) {
    __shared__ float smem[2 * SS];        // dvals[SS] + vals[SS]
    int t = threadIdx.x;

    if (blockIdx.x < BB) {
        float* dvals = smem;
        float* vals  = smem + SS;
        int b = blockIdx.x;

        #pragma unroll
        for (int i = t; i < SS; i += 256)
            dvals[i] = d2[(size_t)b * SS + i];
        __syncthreads();
        #pragma unroll
        for (int i = t; i < SS; i += 256) {
            float v = fmaxf(dvals[pos[(size_t)b * SS + i]], 0.f);
            vals[i] = v;
            detect[(size_t)b * SS + i] = v;
        }
        __syncthreads();

        if (t < 64) {                     // single wave: barrier-free top-k
            int lane = t;
            float sum = 0.f;
            for (int it = 0; it < TOPK; ++it) {
                float lv = -INFINITY;
                int   li = 0x7fffffff;
                #pragma unroll
                for (int c = lane * 4; c < SS; c += 256) {
                    float4 v = *(const float4*)&vals[c];
                    if (v.x > lv) { lv = v.x; li = c; }
                    if (v.y > lv) { lv = v.y; li = c + 1; }
                    if (v.z > lv) { lv = v.z; li = c + 2; }
                    if (v.w > lv) { lv = v.w; li = c + 3; }
                }
                #pragma unroll
                for (int off = 32; off > 0; off >>= 1) {
                    float ov = __shfl_down(lv, off, 64);
                    int   oi = __shfl_down(li, off, 64);
                    if (ov > lv || (ov == lv && oi < li)) { lv = ov; li = oi; }
                }
                lv = __shfl(lv, 0, 64);
                li = __shfl(li, 0, 64);
                sum += lv;
                if (lane == 0) vals[li] = -INFINITY;  // wave-synchronous
            }
            if (lane == 0) meanv[b] = sum / (float)TOPK;
        }
        __syncthreads();
        #pragma unroll
        for (int i = t; i < SS; i += 256) {
            float v = vals[i];
            nontopk[(size_t)b * SS + i] = (v == -INFINITY) ? 0.f : v;
        }
    } else {
        const int nrows = BB * SS;
        const int ncopy = nblocks - BB;
        for (int row = blockIdx.x - BB; row < nrows; row += ncopy) {
            if (counts[row] != 0) continue;
            const vfloat4* bp = (const vfloat4*)(base + (size_t)row * HH) + t;
            vfloat4*       op = (vfloat4*)(mixed + (size_t)row * HH) + t;
            vfloat4 v0 = __builtin_nontemporal_load(bp);
            vfloat4 v1 = __builtin_nontemporal_load(bp + 256);
            __builtin_nontemporal_store(v0, op);
            __builtin_nontemporal_store(v1, op + 256);
        }
    }
}

// ---------------------------------------------------------------------------
// K3: 4 consecutive rows per block; ONLY count>0 rows (~63%):
//   mixed[b,p,:] = base[b,p,:] + counts[b,p]*mean[b]*W[b,:]
// Plain loads (L3 hits from dot), NT stores. Compile-time trip counts.
// ---------------------------------------------------------------------------
__global__ void mix_kernel(const float* __restrict__ base,
                           const float* __restrict__ bw,
                           const int* __restrict__ counts,
                           const float* __restrict__ meanv,
                           float* __restrict__ mixed) {
    int r0 = blockIdx.x << 2;
    int b  = r0 >> 12;                    // / SS
    const float4* w4 = (const float4*)(bw + (size_t)b * HH);
    float mb = meanv[b];
    int t = threadIdx.x;

    #pragma unroll
    for (int k = 0; k < 4; ++k) {
        int r = r0 + k;
        int c = counts[r];
        if (c == 0) continue;             // copied by K2
        float scale = (float)c * mb;
        const float4* b4 = (const float4*)(base + (size_t)r * HH) + t;
        vfloat4*      o4 = (vfloat4*)(mixed + (size_t)r * HH) + t;
        float4 v0 = b4[0];
        float4 v1 = b4[256];
        float4 wv0 = w4[t];
        float4 wv1 = w4[t + 256];
        vfloat4 o0, o1;
        o0.x = v0.x + scale * wv0.x;
        o0.y = v0.y + scale * wv0.y;
        o0.z = v0.z + scale * wv0.z;
        o0.w = v0.w + scale * wv0.w;
        o1.x = v1.x + scale * wv1.x;
        o1.y = v1.y + scale * wv1.y;
        o1.z = v1.z + scale * wv1.z;
        o1.w = v1.w + scale * wv1.w;
        __builtin_nontemporal_store(o0, o4);
        __builtin_nontemporal_store(o1, o4 + 256);
    }
}

// ---------------------------------------------------------------------------
extern "C" void kernel_launch(void* const* d_in, const int* in_sizes, int n_in,
                              void* d_out, int out_size, void* d_ws, size_t ws_size,
                              hipStream_t stream) {
    const float* base = (const float*)d_in[0];
    const int*   pos  = (const int*)d_in[1];
    const float* bw   = (const float*)d_in[2];

    float* out_mixed   = (float*)d_out;
    float* out_detect  = out_mixed + (size_t)BB * SS * HH;
    float* out_nontopk = out_detect + (size_t)BB * SS;

    int*   counts = (int*)d_ws;
    float* d2     = (float*)((char*)d_ws + (size_t)BB * SS * sizeof(int));
    float* meanv  = (float*)((char*)d_ws + 2 * (size_t)BB * SS * sizeof(int));

    const int nrows = BB * SS;
    const int nk2   = BB + 1024;         // 8 topk blocks + 1024 copy blocks

    hist_kernel<<<BB, 256, 0, stream>>>(pos, counts);
    dot_kernel<<<nrows / 4, 256, 0, stream>>>(base, bw, counts, d2);
    topk_copy_kernel<<<nk2, 256, 0, stream>>>(
        d2, pos, counts, base, out_mixed, out_detect, out_nontopk, meanv, nk2);
    mix_kernel<<<nrows / 4, 256, 0, stream>>>(base, bw, counts, meanv, out_mixed);
}